// Round 3
// baseline (5882.702 us; speedup 1.0000x reference)
//
#include <hip/hip_runtime.h>

// Fused 3D conv (64->256ch, 3x3x3, pad1) + bias + pixel-shuffle(+frame-shuffle)
// + repeated-channel skip, for x(1,64,17,128,128) fp32.
// Output (1,32,33,256,256) fp32.
//
// Mapping (derived from the reference's _shuffle3d):
//  f==0: ch = p*128 + q*64 + m (m<32 kept):
//        out[m, 0, 2y+p, 2w+q] = h[ch,0,y,w] + x[(p*64+q*32+m)>>1, 0, y, w]
//  f>=1: ch = a*128 + p*64 + q*32 + m:
//        out[m, 1+2*(f-1)+a, 2y+p, 2w+q] = h[ch,f,y,w] + x[ch>>2, f, y, w]

#define XF 17
#define XH 128
#define XWD 128
#define XCS (XF * XH * XWD)          // x channel stride = 278528
#define OUT_CO_STRIDE (33 * 256 * 256)  // 2162688
#define OUT_F_STRIDE (256 * 256)        // 65536

__global__ __launch_bounds__(256) void conv_shuffle_kernel(
    const float* __restrict__ x, const float* __restrict__ Wt,
    const float* __restrict__ bias, float* __restrict__ out)
{
    const int tid = threadIdx.x;
    const int wx  = tid & 127;       // column 0..127
    const int yr  = tid >> 7;        // row-in-tile 0..1
    int bid = blockIdx.x;
    const int ytile = bid & 63; bid >>= 6;   // 64 tiles of 2 rows
    const int f  = bid % 17;
    const int cg = bid / 17;                 // channel group 0..31
    const int ch0 = cg << 3;                 // 8 channels per thread

    // frame-0 path discards channels with (ch & 32) != 0 (hf truncation)
    if (f == 0 && (ch0 & 32)) return;

    const int y = ytile * 2 + yr;

    float acc[8];
#pragma unroll
    for (int j = 0; j < 8; ++j) acc[j] = bias[ch0 + j];

    for (int ic = 0; ic < 64; ++ic) {
        const float* xc = x + ic * XCS;
#pragma unroll
        for (int kf = 0; kf < 3; ++kf) {
            const int zf = f + kf - 1;
            if (zf < 0 || zf >= XF) continue;     // block-uniform
#pragma unroll
            for (int kh = 0; kh < 3; ++kh) {
                const int zy = y + kh - 1;
                const bool vy = (zy >= 0) && (zy < XH);
                const float* xr = xc + zf * (XH * XWD) + (vy ? zy : 0) * XWD;
                const float xm1 = (vy && wx > 0)   ? xr[wx - 1] : 0.0f;
                const float x0  = vy               ? xr[wx]     : 0.0f;
                const float xp1 = (vy && wx < 127) ? xr[wx + 1] : 0.0f;
                const float* wr = Wt + ch0 * 1728 + ic * 27 + kf * 9 + kh * 3;
#pragma unroll
                for (int j = 0; j < 8; ++j) {
                    const float w0 = wr[j * 1728 + 0];
                    const float w1 = wr[j * 1728 + 1];
                    const float w2 = wr[j * 1728 + 2];
                    acc[j] = fmaf(xm1, w0, acc[j]);
                    acc[j] = fmaf(x0,  w1, acc[j]);
                    acc[j] = fmaf(xp1, w2, acc[j]);
                }
            }
        }
    }

    // scatter (shuffle) + skip
    if (f == 0) {
#pragma unroll
        for (int j = 0; j < 8; ++j) {
            const int ch = ch0 + j;
            const int p = ch >> 7, q = (ch >> 6) & 1, m = ch & 63;  // m<32 here
            const float sk = x[((p * 64 + q * 32 + m) >> 1) * XCS + y * XWD + wx];
            out[(size_t)m * OUT_CO_STRIDE + (size_t)(2 * y + p) * 256 + (2 * wx + q)]
                = acc[j] + sk;
        }
    } else {
#pragma unroll
        for (int j = 0; j < 8; ++j) {
            const int ch = ch0 + j;
            const int a = ch >> 7, p = (ch >> 6) & 1, q = (ch >> 5) & 1, m = ch & 31;
            const int fo = 1 + (f - 1) * 2 + a;
            const float sk = x[(ch >> 2) * XCS + f * (XH * XWD) + y * XWD + wx];
            out[(size_t)m * OUT_CO_STRIDE + (size_t)fo * OUT_F_STRIDE
                + (size_t)(2 * y + p) * 256 + (2 * wx + q)] = acc[j] + sk;
        }
    }
}

extern "C" void kernel_launch(void* const* d_in, const int* in_sizes, int n_in,
                              void* d_out, int out_size, void* d_ws, size_t ws_size,
                              hipStream_t stream) {
    const float* x  = (const float*)d_in[0];
    const float* Wt = (const float*)d_in[1];
    const float* b  = (const float*)d_in[2];
    float* out = (float*)d_out;

    const int grid = 32 * 17 * 64;  // cg(32) * f(17) * ytile(64)
    conv_shuffle_kernel<<<dim3(grid), dim3(256), 0, stream>>>(x, Wt, b, out);
}

// Round 5
// 1064.318 us; speedup vs baseline: 5.5272x; 5.5272x over previous
//
#include <hip/hip_runtime.h>

// Round 4 (resubmit): MFMA implicit-GEMM version.
// conv3d(64->256, 3x3x3, pad1) + bias + pixel/frame shuffle + repeated skip.
// x (1,64,17,128,128) fp32  ->  out (1,32,33,256,256) fp32.
//
// prep_w : Wb[tap][ch][ic]  bf16   (27*256*64)            @ d_ws + 0
// prep_x : xT[f][y][w][ic]  bf16   (17*128*128*64)        @ d_ws + 1MB
// conv_mfma : per (f,y): C[256ch x 128w] = sum over taps/ic, MFMA 16x16x32 bf16,
//             fragments loaded directly from global (no LDS, no barriers).

#define XF 17
#define XH 128
#define XWD 128
#define XCS (XF * XH * XWD)      // 278528
#define OCS (33 * 256 * 256)     // out channel stride
#define OFS (256 * 256)          // out frame stride

typedef short short8 __attribute__((ext_vector_type(8)));
typedef float f32x4 __attribute__((ext_vector_type(4)));

__device__ inline unsigned short f2bf(float v) {
    union { float f; unsigned u; } c; c.f = v;
    unsigned r = c.u + 0x7FFFu + ((c.u >> 16) & 1u);   // round-to-nearest-even
    return (unsigned short)(r >> 16);
}

// ---- prep: W fp32 [ch][ic][kf][kh][kw] -> bf16 Wb[tap][ch][ic] ----
__global__ __launch_bounds__(256) void prep_w(const float* __restrict__ Wf,
                                              unsigned short* __restrict__ Wb) {
    const int idx = blockIdx.x * 256 + threadIdx.x;     // = tap*16384 + ch*64 + ic
    const int ic = idx & 63, ch = (idx >> 6) & 255, t = idx >> 14;
    Wb[idx] = f2bf(Wf[(ch * 64 + ic) * 27 + t]);
}

// ---- prep: x fp32 [ic][f][y][w] -> bf16 xT[f][y][w][ic] ----
__global__ __launch_bounds__(256) void prep_x(const float* __restrict__ x,
                                              unsigned short* __restrict__ xT) {
    __shared__ unsigned short lds[128][72];             // +8 pad: 16B-aligned rows, banks spread
    const int f = blockIdx.x >> 7, y = blockIdx.x & 127;
    const int tid = threadIdx.x;
    const int w = tid & 127;
#pragma unroll
    for (int rep = 0; rep < 32; ++rep) {
        const int ic = rep * 2 + (tid >> 7);
        lds[w][ic] = f2bf(x[(size_t)ic * XCS + f * (XH * XWD) + y * XWD + w]);
    }
    __syncthreads();
    unsigned short* dst = xT + (size_t)(f * 128 + y) * 8192;
    const int icg = tid & 7;
#pragma unroll
    for (int rep = 0; rep < 4; ++rep) {
        const int ww = rep * 32 + (tid >> 3);
        *(short8*)(dst + ww * 64 + icg * 8) = *(const short8*)(&lds[ww][icg * 8]);
    }
}

// ---- main: implicit GEMM, block = (f,y), 4 waves = 2M x 2N, tile 256ch x 128w ----
__global__ __launch_bounds__(256, 2) void conv_mfma(
    const float* __restrict__ x, const unsigned short* __restrict__ Wb,
    const float* __restrict__ bias, const unsigned short* __restrict__ xT,
    float* __restrict__ out)
{
    const int tid = threadIdx.x;
    const int lane = tid & 63, lr = lane & 15, lg = lane >> 4;
    const int wv = tid >> 6, wm = wv >> 1, wn = wv & 1;
    const int f = blockIdx.x >> 7, y = blockIdx.x & 127;

    f32x4 acc[8][4];
#pragma unroll
    for (int mm = 0; mm < 8; ++mm)
#pragma unroll
        for (int nn = 0; nn < 4; ++nn) {
            f32x4 z = {0.f, 0.f, 0.f, 0.f};
            acc[mm][nn] = z;
        }
    const short8 zeroB = {0, 0, 0, 0, 0, 0, 0, 0};

#pragma unroll 1
    for (int kf = 0; kf < 3; ++kf) {
        const int zf = f + kf - 1;
        if (zf < 0 || zf >= XF) continue;
#pragma unroll 1
        for (int kh = 0; kh < 3; ++kh) {
            const int zy = y + kh - 1;
            if (zy < 0 || zy >= XH) continue;
            const unsigned short* xs = xT + (size_t)(zf * 128 + zy) * 8192;
            const unsigned short* wt0 = Wb + (kf * 3 + kh) * 3 * 16384;
#pragma unroll
            for (int kw = 0; kw < 3; ++kw) {
                const unsigned short* wt = wt0 + kw * 16384;
#pragma unroll
                for (int ks = 0; ks < 2; ++ks) {
                    short8 a[8], b[4];
#pragma unroll
                    for (int mm = 0; mm < 8; ++mm)
                        a[mm] = *(const short8*)(wt + (wm * 128 + mm * 16 + lr) * 64
                                                 + ks * 32 + lg * 8);
#pragma unroll
                    for (int nn = 0; nn < 4; ++nn) {
                        const int wc = wn * 64 + nn * 16 + lr + kw - 1;
                        b[nn] = (wc >= 0 && wc < XWD)
                              ? *(const short8*)(xs + wc * 64 + ks * 32 + lg * 8)
                              : zeroB;
                    }
#pragma unroll
                    for (int mm = 0; mm < 8; ++mm)
#pragma unroll
                        for (int nn = 0; nn < 4; ++nn)
                            acc[mm][nn] = __builtin_amdgcn_mfma_f32_16x16x32_bf16(
                                a[mm], b[nn], acc[mm][nn], 0, 0, 0);
                }
            }
        }
    }

    // ---- epilogue: bias + shuffle scatter + skip (same algebra as verified baseline) ----
#pragma unroll
    for (int mm = 0; mm < 8; ++mm) {
        const int chb = wm * 128 + mm * 16 + lg * 4;
#pragma unroll
        for (int nn = 0; nn < 4; ++nn) {
            const int wcol = wn * 64 + nn * 16 + lr;
#pragma unroll
            for (int r = 0; r < 4; ++r) {
                const int ch = chb + r;
                const float h = acc[mm][nn][r] + bias[ch];
                if (f == 0) {
                    if (ch & 32) continue;   // frame-0 truncated channels
                    const int p = ch >> 7, q = (ch >> 6) & 1, m = ch & 31;
                    const float sk = x[(size_t)((p * 64 + q * 32 + m) >> 1) * XCS
                                       + y * XWD + wcol];
                    out[(size_t)m * OCS + (size_t)(2 * y + p) * 256 + 2 * wcol + q]
                        = h + sk;
                } else {
                    const int aa = ch >> 7, p = (ch >> 6) & 1, q = (ch >> 5) & 1,
                              m = ch & 31;
                    const int fo = 1 + 2 * (f - 1) + aa;
                    const float sk = x[(size_t)(ch >> 2) * XCS
                                       + (size_t)f * (XH * XWD) + y * XWD + wcol];
                    out[(size_t)m * OCS + (size_t)fo * OFS
                        + (size_t)(2 * y + p) * 256 + 2 * wcol + q] = h + sk;
                }
            }
        }
    }
}

extern "C" void kernel_launch(void* const* d_in, const int* in_sizes, int n_in,
                              void* d_out, int out_size, void* d_ws, size_t ws_size,
                              hipStream_t stream) {
    const float* x  = (const float*)d_in[0];
    const float* Wf = (const float*)d_in[1];
    const float* b  = (const float*)d_in[2];
    float* out = (float*)d_out;

    unsigned short* Wb = (unsigned short*)d_ws;                         // 884,736 B
    unsigned short* xT = (unsigned short*)((char*)d_ws + (1 << 20));    // 35.65 MB

    prep_w<<<dim3(1728), dim3(256), 0, stream>>>(Wf, Wb);
    prep_x<<<dim3(17 * 128), dim3(256), 0, stream>>>(x, xT);
    conv_mfma<<<dim3(17 * 128), dim3(256), 0, stream>>>(x, Wb, b, xT, out);
}

// Round 7
// 912.138 us; speedup vs baseline: 6.4494x; 1.1668x over previous
//
#include <hip/hip_runtime.h>

// Round 6 (resubmit): implicit-GEMM MFMA + LDS-staged B rows (double-buffered,
// T14 split) + XCD-chunked block swizzle.
// conv3d(64->256, 3x3x3, pad1) + bias + pixel/frame shuffle + repeated skip.

#define XF 17
#define XH 128
#define XWD 128
#define XCS (XF * XH * XWD)      // 278528
#define OCS (33 * 256 * 256)
#define OFS (256 * 256)

typedef short short8 __attribute__((ext_vector_type(8)));
typedef float f32x4 __attribute__((ext_vector_type(4)));

__device__ inline unsigned short f2bf(float v) {
    union { float f; unsigned u; } c; c.f = v;
    unsigned r = c.u + 0x7FFFu + ((c.u >> 16) & 1u);
    return (unsigned short)(r >> 16);
}

__global__ __launch_bounds__(256) void prep_w(const float* __restrict__ Wf,
                                              unsigned short* __restrict__ Wb) {
    const int idx = blockIdx.x * 256 + threadIdx.x;     // tap*16384 + ch*64 + ic
    const int ic = idx & 63, ch = (idx >> 6) & 255, t = idx >> 14;
    Wb[idx] = f2bf(Wf[(ch * 64 + ic) * 27 + t]);
}

__global__ __launch_bounds__(256) void prep_x(const float* __restrict__ x,
                                              unsigned short* __restrict__ xT) {
    __shared__ unsigned short l[128][72];
    const int f = blockIdx.x >> 7, y = blockIdx.x & 127;
    const int tid = threadIdx.x;
    const int w = tid & 127;
#pragma unroll
    for (int rep = 0; rep < 32; ++rep) {
        const int ic = rep * 2 + (tid >> 7);
        l[w][ic] = f2bf(x[(size_t)ic * XCS + f * (XH * XWD) + y * XWD + w]);
    }
    __syncthreads();
    unsigned short* dst = xT + (size_t)(f * 128 + y) * 8192;
    const int icg = tid & 7;
#pragma unroll
    for (int rep = 0; rep < 4; ++rep) {
        const int ww = rep * 32 + (tid >> 3);
        *(short8*)(dst + ww * 64 + icg * 8) = *(const short8*)(&l[ww][icg * 8]);
    }
}

// main: block=(f,y) [XCD-swizzled], 4 waves = 2M x 2N, C-tile 256ch x 128w.
// B rows (xT, 128 w-cols x 64 ic) staged in LDS [130][72] (halo + pad),
// double-buffered across the valid (kf,kh) groups; A direct from global (L2-hot).
__global__ __launch_bounds__(256, 2) void conv_mfma(
    const float* __restrict__ x, const unsigned short* __restrict__ Wb,
    const float* __restrict__ bias, const unsigned short* __restrict__ xT,
    float* __restrict__ out)
{
    __shared__ unsigned short lds[2][9360];   // 2 x 130 rows x 72 shorts (37.4 KB)

    const int tid = threadIdx.x;
    const int lane = tid & 63, lr = lane & 15, lg = lane >> 4;
    const int wv = tid >> 6, wm = wv >> 1, wn = wv & 1;

    // XCD-chunked bijective swizzle: 2176 blocks = 8 XCDs x 272
    const int bid = blockIdx.x;
    const int sbid = (bid & 7) * 272 + (bid >> 3);
    const int f = sbid >> 7, y = sbid & 127;

    // valid tap ranges (block-uniform, contiguous)
    const int kf0 = (f == 0) ? 1 : 0, kf1 = (f == XF - 1) ? 1 : 2;
    const int kh0 = (y == 0) ? 1 : 0, kh1 = (y == XH - 1) ? 1 : 2;

    // zero halo rows (w=-1 and w=128) of both buffers
    if (tid < 36) {
        const int b = tid / 18, rr = (tid % 18) / 9, k = tid % 9;
        const short8 zz = {0, 0, 0, 0, 0, 0, 0, 0};
        *(short8*)(&lds[b][(rr ? 129 * 72 : 0) + k * 8]) = zz;
    }

    // per-thread staging slot: col = 1+(tid>>1), ic-half = (tid&1)*32
    const int scol = 1 + (tid >> 1);
    const int sic  = (tid & 1) * 32;

    // stage first group into buffer 0
    {
        const unsigned short* s = xT + (size_t)((f + kf0 - 1) * 128 + (y + kh0 - 1)) * 8192
                                  + (tid >> 1) * 64 + sic;
        short8 v0 = *(const short8*)(s);
        short8 v1 = *(const short8*)(s + 8);
        short8 v2 = *(const short8*)(s + 16);
        short8 v3 = *(const short8*)(s + 24);
        unsigned short* d = &lds[0][scol * 72 + sic];
        *(short8*)(d) = v0; *(short8*)(d + 8) = v1;
        *(short8*)(d + 16) = v2; *(short8*)(d + 24) = v3;
    }
    __syncthreads();

    f32x4 acc[8][4];
#pragma unroll
    for (int mm = 0; mm < 8; ++mm)
#pragma unroll
        for (int nn = 0; nn < 4; ++nn) {
            f32x4 z = {0.f, 0.f, 0.f, 0.f};
            acc[mm][nn] = z;
        }

    int gi = 0;   // staged-group parity counter
#pragma unroll 1
    for (int kf = kf0; kf <= kf1; ++kf) {
#pragma unroll 1
        for (int kh = kh0; kh <= kh1; ++kh, ++gi) {
            const int cb = gi & 1;

            // next group (prefetch target)
            int nkf = kf, nkh = kh + 1;
            if (nkh > kh1) { nkf = kf + 1; nkh = kh0; }
            const bool hasNext = (nkf <= kf1);

            // T14: issue next-row global loads EARLY (hide under MFMAs)
            short8 pf0, pf1, pf2, pf3;
            if (hasNext) {
                const unsigned short* s = xT
                    + (size_t)((f + nkf - 1) * 128 + (y + nkh - 1)) * 8192
                    + (tid >> 1) * 64 + sic;
                pf0 = *(const short8*)(s);
                pf1 = *(const short8*)(s + 8);
                pf2 = *(const short8*)(s + 16);
                pf3 = *(const short8*)(s + 24);
            }

            const unsigned short* wt0 = Wb + (size_t)(kf * 3 + kh) * 3 * 16384;
#pragma unroll
            for (int kw = 0; kw < 3; ++kw) {
                const unsigned short* wt = wt0 + kw * 16384;
#pragma unroll
                for (int ks = 0; ks < 2; ++ks) {
                    short8 a[8], b[4];
#pragma unroll
                    for (int mm = 0; mm < 8; ++mm)
                        a[mm] = *(const short8*)(wt + (wm * 128 + mm * 16 + lr) * 64
                                                 + ks * 32 + lg * 8);
#pragma unroll
                    for (int nn = 0; nn < 4; ++nn) {
                        const int col = wn * 64 + nn * 16 + lr + kw;  // halo-shifted
                        b[nn] = *(const short8*)(&lds[cb][col * 72 + ks * 32 + lg * 8]);
                    }
#pragma unroll
                    for (int mm = 0; mm < 8; ++mm)
#pragma unroll
                        for (int nn = 0; nn < 4; ++nn)
                            acc[mm][nn] = __builtin_amdgcn_mfma_f32_16x16x32_bf16(
                                a[mm], b[nn], acc[mm][nn], 0, 0, 0);
                }
            }

            // write prefetched row into the other buffer, one barrier per group
            if (hasNext) {
                unsigned short* d = &lds[cb ^ 1][scol * 72 + sic];
                *(short8*)(d) = pf0; *(short8*)(d + 8) = pf1;
                *(short8*)(d + 16) = pf2; *(short8*)(d + 24) = pf3;
                __syncthreads();
            }
        }
    }

    // epilogue: bias + shuffle scatter + skip (verified algebra)
#pragma unroll
    for (int mm = 0; mm < 8; ++mm) {
        const int chb = wm * 128 + mm * 16 + lg * 4;
#pragma unroll
        for (int nn = 0; nn < 4; ++nn) {
            const int wcol = wn * 64 + nn * 16 + lr;
#pragma unroll
            for (int r = 0; r < 4; ++r) {
                const int ch = chb + r;
                const float h = acc[mm][nn][r] + bias[ch];
                if (f == 0) {
                    if (ch & 32) continue;
                    const int p = ch >> 7, q = (ch >> 6) & 1, m = ch & 31;
                    const float sk = x[(size_t)((p * 64 + q * 32 + m) >> 1) * XCS
                                       + y * XWD + wcol];
                    out[(size_t)m * OCS + (size_t)(2 * y + p) * 256 + 2 * wcol + q]
                        = h + sk;
                } else {
                    const int aa = ch >> 7, p = (ch >> 6) & 1, q = (ch >> 5) & 1,
                              m = ch & 31;
                    const int fo = 1 + 2 * (f - 1) + aa;
                    const float sk = x[(size_t)(ch >> 2) * XCS
                                       + (size_t)f * (XH * XWD) + y * XWD + wcol];
                    out[(size_t)m * OCS + (size_t)fo * OFS
                        + (size_t)(2 * y + p) * 256 + 2 * wcol + q] = h + sk;
                }
            }
        }
    }
}

extern "C" void kernel_launch(void* const* d_in, const int* in_sizes, int n_in,
                              void* d_out, int out_size, void* d_ws, size_t ws_size,
                              hipStream_t stream) {
    const float* x  = (const float*)d_in[0];
    const float* Wf = (const float*)d_in[1];
    const float* b  = (const float*)d_in[2];
    float* out = (float*)d_out;

    unsigned short* Wb = (unsigned short*)d_ws;                         // 884,736 B
    unsigned short* xT = (unsigned short*)((char*)d_ws + (1 << 20));    // 35.65 MB

    prep_w<<<dim3(1728), dim3(256), 0, stream>>>(Wf, Wb);
    prep_x<<<dim3(17 * 128), dim3(256), 0, stream>>>(x, xT);
    conv_mfma<<<dim3(17 * 128), dim3(256), 0, stream>>>(x, Wb, b, xT, out);
}